// Round 4
// baseline (251.836 us; speedup 1.0000x reference)
//
#include <hip/hip_runtime.h>
#include <hip/hip_bf16.h>
#include <stdint.h>

typedef __bf16 bf16x8 __attribute__((ext_vector_type(8)));
typedef float f32x4 __attribute__((ext_vector_type(4)));
typedef float f32x16 __attribute__((ext_vector_type(16)));
typedef unsigned int uint2v __attribute__((ext_vector_type(2)));

#define E_DIM 1024
#define HD 64
#define NH 16
#define QKV_LD 1152
#define KSPLIT 2
#define LOG2E 1.44269504088896f

__device__ __forceinline__ float toF(float x) { return x; }
__device__ __forceinline__ float toF(__hip_bfloat16 x) { return __bfloat162float(x); }
__device__ __forceinline__ void storeOut(float* p, float v) { *p = v; }
__device__ __forceinline__ void storeOut(__hip_bfloat16* p, float v) { *p = __float2bfloat16(v); }

__device__ __forceinline__ unsigned cvtpk_bf16(float lo, float hi_) {
    unsigned r;
    asm("v_cvt_pk_bf16_f32 %0, %1, %2" : "=v"(r) : "v"(lo), "v"(hi_));
    return r;
}
__device__ __forceinline__ void perm32swap(unsigned& a, unsigned& b) {
    uint2v r = __builtin_amdgcn_permlane32_swap(a, b, false, false);
    a = r.x; b = r.y;
}
__device__ __forceinline__ float fexp2(float x) {
    float r;
    asm("v_exp_f32 %0, %1" : "=v"(r) : "v"(x));
    return r;
}

typedef __attribute__((address_space(1))) void gvoid;
typedef __attribute__((address_space(3))) void lvoid;
__device__ __forceinline__ void gload_lds16(const void* g, void* l) {
    __builtin_amdgcn_global_load_lds((gvoid*)g, (lvoid*)l, 16, 0, 0);
}

// ---------------- cast fp32 -> bf16 (vectorized) ----------------
__global__ void cast_f32_bf16_kernel(const float* __restrict__ in, __hip_bfloat16* __restrict__ o, int n) {
    int i = (blockIdx.x * blockDim.x + threadIdx.x) * 4;
    if (i + 3 < n) {
        float4 v = *reinterpret_cast<const float4*>(in + i);
        __hip_bfloat16 t[4] = {__float2bfloat16(v.x), __float2bfloat16(v.y),
                               __float2bfloat16(v.z), __float2bfloat16(v.w)};
        *reinterpret_cast<uint2*>(o + i) = *reinterpret_cast<uint2*>(t);
    }
}

// ---------------- tiled cast-transpose: out[c][r] = in[r][c] ----------------
template<typename InT>
__global__ void transpose_cast_kernel(const InT* __restrict__ in, int ldi,
                                      __hip_bfloat16* __restrict__ out, int ldo,
                                      int R, int C) {
    __shared__ float tile[32][33];
    const int bx = blockIdx.x * 32;  // r
    const int by = blockIdx.y * 32;  // c
    const int tx = threadIdx.x & 31, ty = threadIdx.x >> 5;  // 32 x 8
#pragma unroll
    for (int j = 0; j < 4; ++j) {
        int r = bx + ty + j * 8, c = by + tx;
        tile[ty + j * 8][tx] = toF(in[(size_t)r * ldi + c]);
    }
    __syncthreads();
#pragma unroll
    for (int j = 0; j < 4; ++j) {
        int c = by + ty + j * 8, r = bx + tx;
        out[(size_t)c * ldo + r] = __float2bfloat16(tile[tx][ty + j * 8]);
    }
}

// ---------------- bqkv = [bq | bk | bv] ----------------
__global__ void concat_bias3_kernel(const float* __restrict__ bq, const float* __restrict__ bk,
                                    const float* __restrict__ bv, float* __restrict__ bqkv) {
    int i = blockIdx.x * blockDim.x + threadIdx.x;
    if (i < E_DIM) bqkv[i] = bq[i];
    else if (i < E_DIM + HD) bqkv[i] = bk[i - E_DIM];
    else if (i < E_DIM + 2 * HD) bqkv[i] = bv[i - E_DIM - HD];
}

// ---------------- mask -> 64-bit words via ballot ----------------
__global__ void maskbits_kernel(const int* __restrict__ mask, unsigned long long* __restrict__ mb,
                                int nwords) {
    int gtid = blockIdx.x * blockDim.x + threadIdx.x;
    int wid = gtid >> 6, lane = gtid & 63;
    int nw = (gridDim.x * blockDim.x) >> 6;
    for (int w = wid; w < nwords; w += nw) {
        int v = mask[(size_t)w * 64 + lane];
        unsigned long long b = __ballot(v != 0);
        if (lane == 0) mb[w] = b;
    }
}

// ---------------- bf16 GEMM: C[M][N] = A[M][K] * Bt[N][K]^T ----------------
// epilogue: (acc + bias[col]) * (col < nQ ? sQ : sKV)
template<typename OutT>
__global__ __launch_bounds__(256)
void gemm_bt_kernel(const __hip_bfloat16* __restrict__ A,
                    const __hip_bfloat16* __restrict__ Bt,
                    const float* __restrict__ bias,
                    OutT* __restrict__ C,
                    int M, int N, int K, float sQ, int nQ, float sKV) {
    constexpr int BM = 128, BN = 128, BK = 32;
    __shared__ __align__(16) unsigned char lA[BM * BK * 2];  // [row][64B] swizzled
    __shared__ __align__(16) unsigned char lB[BN * BK * 2];
    const int ntn = N / BN;
    const int tm = blockIdx.x / ntn, tn = blockIdx.x % ntn;
    const int tid = threadIdx.x, lane = tid & 63, wave = tid >> 6;
    const int l15 = lane & 15, l4 = lane >> 4;
    const int wm = (wave >> 1) * 64, wn = (wave & 1) * 64;
    const int r0 = tm * BM, c0 = tn * BN;
    f32x4 z4 = {0.f, 0.f, 0.f, 0.f};
    f32x4 acc[4][4];
#pragma unroll
    for (int mi = 0; mi < 4; ++mi)
#pragma unroll
        for (int ni = 0; ni < 4; ++ni) acc[mi][ni] = z4;

    for (int k0 = 0; k0 < K; k0 += BK) {
#pragma unroll
        for (int i = 0; i < 2; ++i) {
            int id = tid + i * 256;        // 0..511 : 16B chunks
            int row = id >> 2;             // 0..127
            int cb = (id & 3) * 16;        // byte in 64B row
            int sw = cb ^ ((row & 3) << 4);
            uint4 va = *reinterpret_cast<const uint4*>(
                reinterpret_cast<const unsigned char*>(A + (size_t)(r0 + row) * K + k0) + cb);
            *reinterpret_cast<uint4*>(&lA[row * 64 + sw]) = va;
            uint4 vb = *reinterpret_cast<const uint4*>(
                reinterpret_cast<const unsigned char*>(Bt + (size_t)(c0 + row) * K + k0) + cb);
            *reinterpret_cast<uint4*>(&lB[row * 64 + sw]) = vb;
        }
        __syncthreads();
        bf16x8 af[4], bf[4];
#pragma unroll
        for (int mi = 0; mi < 4; ++mi) {
            int row = wm + mi * 16 + l15;
            af[mi] = *reinterpret_cast<const bf16x8*>(&lA[row * 64 + ((l4 * 16) ^ ((row & 3) << 4))]);
        }
#pragma unroll
        for (int ni = 0; ni < 4; ++ni) {
            int row = wn + ni * 16 + l15;
            bf[ni] = *reinterpret_cast<const bf16x8*>(&lB[row * 64 + ((l4 * 16) ^ ((row & 3) << 4))]);
        }
#pragma unroll
        for (int mi = 0; mi < 4; ++mi)
#pragma unroll
            for (int ni = 0; ni < 4; ++ni)
                acc[mi][ni] = __builtin_amdgcn_mfma_f32_16x16x32_bf16(af[mi], bf[ni], acc[mi][ni], 0, 0, 0);
        __syncthreads();
    }
#pragma unroll
    for (int ni = 0; ni < 4; ++ni) {
        int col = c0 + wn + ni * 16 + l15;
        float b = bias[col];
        float s = (col < nQ) ? sQ : sKV;
#pragma unroll
        for (int mi = 0; mi < 4; ++mi) {
            int row = r0 + wm + mi * 16 + l4 * 4;
#pragma unroll
            for (int r = 0; r < 4; ++r) {
                float v = (acc[mi][ni][r] + b) * s;
                storeOut(C + (size_t)(row + r) * N + col, v);
            }
        }
    }
}

// ---------------- MQA flash attention v4 (K-split flash-decoding) ----------------
// grid (S/32, NH/4, KSPLIT). 4 waves/block, wave = head, 32 q-rows. Swapped QK^T,
// Oᵀ PV, log2-domain softmax, defer-max, gload_lds staging with pre-swizzled source.
// Writes unnormalized fp32 O partial + (m,l) per (split,q,h).
__global__ __launch_bounds__(256, 4)
void mqa4_kernel(const __hip_bfloat16* __restrict__ qkv,   // [S][1152], q prescaled
                 const __hip_bfloat16* __restrict__ vtb,   // [64][S]
                 const unsigned long long* __restrict__ mbits,
                 float* __restrict__ po,                   // [KSPLIT][S][1024]
                 float* __restrict__ ml,                   // [KSPLIT][S][NH][2]
                 int S) {
    __shared__ __align__(16) unsigned char sKV[2][16384];
    const int tid = threadIdx.x, lane = tid & 63, w = tid >> 6;
    const int r31 = lane & 31, hi = lane >> 5, rx = r31 & 15;
    const int q0 = blockIdx.x * 32;
    const int h = blockIdx.y * 4 + w;
    const int split = blockIdx.z;
    const int NTtot = S / 64, NT = NTtot / KSPLIT;
    const int k0base = split * (S / KSPLIT);
    const __hip_bfloat16* kvb = qkv + E_DIM;

    // Q fragments (prescaled by 0.125*log2e in the fused GEMM)
    bf16x8 qf[4];
    {
        const __hip_bfloat16* qp = qkv + (size_t)(q0 + r31) * QKV_LD + h * HD + hi * 8;
#pragma unroll
        for (int s = 0; s < 4; ++s) qf[s] = *reinterpret_cast<const bf16x8*>(qp + 16 * s);
    }

    // staging: wave w owns tile rows [w*16, w*16+16) -> 4 x 1KB global_load_lds_dwordx4
    const char* gbase[4];
    int gstep[4];
    unsigned ldsoff[4];
#pragma unroll
    for (int i = 0; i < 4; ++i) {
        int r = w * 16 + i * 4 + (lane >> 4);
        int sl = lane & 15;            // LDS 16B slot
        int c = sl ^ (r & 15);         // global chunk that lands in this slot
        if (c < 8) {
            gbase[i] = (const char*)(kvb + (size_t)(k0base + r) * QKV_LD + c * 8);
            gstep[i] = 64 * QKV_LD * 2;
        } else {
            gbase[i] = (const char*)(vtb + (size_t)r * S + k0base + (c - 8) * 8);
            gstep[i] = 128;
        }
        ldsoff[i] = w * 4096 + i * 1024;
    }

    // prologue: stage tile 0
#pragma unroll
    for (int i = 0; i < 4; ++i) { gload_lds16(gbase[i], &sKV[0][ldsoff[i]]); gbase[i] += gstep[i]; }
    __syncthreads();

    float rm = -3e38f, rl = 0.f;
    f32x16 oacc[2];
#pragma unroll
    for (int i = 0; i < 16; ++i) { oacc[0][i] = 0.f; oacc[1][i] = 0.f; }

    int buf = 0;
    for (int t = 0; t < NT; ++t) {
        // stage tile t+1 into other buffer (drained by end-of-iter barrier)
        if (t + 1 < NT) {
#pragma unroll
            for (int i = 0; i < 4; ++i) { gload_lds16(gbase[i], &sKV[buf ^ 1][ldsoff[i]]); gbase[i] += gstep[i]; }
        }
        unsigned long long wb = mbits[(size_t)(q0 + r31) * NTtot + split * NT + t];
        const unsigned char* bp = sKV[buf];

        // ---- QK^T: sacc[kb][reg] = S_log2[k = kb*32 + crow(reg,hi)][q = r31]
        f32x16 sacc[2];
#pragma unroll
        for (int kb = 0; kb < 2; ++kb) {
            const unsigned char* rowp = bp + (kb * 32 + r31) * 256;
            f32x16 a;
#pragma unroll
            for (int i = 0; i < 16; ++i) a[i] = 0.f;
#pragma unroll
            for (int s = 0; s < 4; ++s) {
                int slot = (2 * s + hi) ^ rx;
                bf16x8 kf = *reinterpret_cast<const bf16x8*>(rowp + slot * 16);
                a = __builtin_amdgcn_mfma_f32_32x32x16_bf16(kf, qf[s], a, 0, 0, 0);
            }
            sacc[kb] = a;
        }

        // ---- mask (free when all-ones); -10000 * log2e
        if (wb != ~0ull) {
#pragma unroll
            for (int r = 0; r < 16; ++r) {
                int kl = (r & 3) + 8 * (r >> 2) + 4 * hi;
                if (!((wb >> kl) & 1)) sacc[0][r] = -14427.0f;
                if (!((wb >> (kl + 32)) & 1)) sacc[1][r] = -14427.0f;
            }
        }

        // ---- tile max (ILP tree) + one cross-half exchange
        float t0[8];
#pragma unroll
        for (int j = 0; j < 8; ++j)
            t0[j] = fmaxf(fmaxf(sacc[0][j], sacc[0][j + 8]), fmaxf(sacc[1][j], sacc[1][j + 8]));
        float u0 = fmaxf(t0[0], t0[4]), u1 = fmaxf(t0[1], t0[5]);
        float u2 = fmaxf(t0[2], t0[6]), u3 = fmaxf(t0[3], t0[7]);
        float pmax = fmaxf(fmaxf(u0, u1), fmaxf(u2, u3));
        pmax = fmaxf(pmax, __shfl_xor(pmax, 32));

        // ---- defer-max: rescale only when needed (wave-uniform branch)
        if (!__all(pmax - rm <= 8.0f)) {
            float rmn = fmaxf(rm, pmax);
            float al = fexp2(rm - rmn);
            rl *= al;
#pragma unroll
            for (int r = 0; r < 16; ++r) { oacc[0][r] *= al; oacc[1][r] *= al; }
            rm = rmn;
        }

        // ---- p = exp2(s - rm), 4-way partial sums
        float s0 = 0.f, s1 = 0.f, s2 = 0.f, s3 = 0.f;
#pragma unroll
        for (int r = 0; r < 16; r += 4) {
            sacc[0][r + 0] = fexp2(sacc[0][r + 0] - rm); s0 += sacc[0][r + 0];
            sacc[0][r + 1] = fexp2(sacc[0][r + 1] - rm); s1 += sacc[0][r + 1];
            sacc[0][r + 2] = fexp2(sacc[0][r + 2] - rm); s2 += sacc[0][r + 2];
            sacc[0][r + 3] = fexp2(sacc[0][r + 3] - rm); s3 += sacc[0][r + 3];
        }
#pragma unroll
        for (int r = 0; r < 16; r += 4) {
            sacc[1][r + 0] = fexp2(sacc[1][r + 0] - rm); s0 += sacc[1][r + 0];
            sacc[1][r + 1] = fexp2(sacc[1][r + 1] - rm); s1 += sacc[1][r + 1];
            sacc[1][r + 2] = fexp2(sacc[1][r + 2] - rm); s2 += sacc[1][r + 2];
            sacc[1][r + 3] = fexp2(sacc[1][r + 3] - rm); s3 += sacc[1][r + 3];
        }
        float sum = (s0 + s1) + (s2 + s3);
        sum += __shfl_xor(sum, 32);
        rl += sum;

        // ---- P -> bf16 A-frags: pa[s] holds P[q=r31][k = 16s + hi*8 + j]
        bf16x8 pa[4];
#pragma unroll
        for (int kb = 0; kb < 2; ++kb) {
#pragma unroll
            for (int half = 0; half < 2; ++half) {
                int b0 = half * 8;
                unsigned A = cvtpk_bf16(sacc[kb][b0 + 0], sacc[kb][b0 + 1]);
                unsigned B = cvtpk_bf16(sacc[kb][b0 + 2], sacc[kb][b0 + 3]);
                unsigned C = cvtpk_bf16(sacc[kb][b0 + 4], sacc[kb][b0 + 5]);
                unsigned D = cvtpk_bf16(sacc[kb][b0 + 6], sacc[kb][b0 + 7]);
                perm32swap(A, C);
                perm32swap(B, D);
                union { unsigned u[4]; bf16x8 v; } pk;
                pk.u[0] = A; pk.u[1] = B; pk.u[2] = C; pk.u[3] = D;
                pa[kb * 2 + half] = pk.v;
            }
        }

        // ---- PV (Oᵀ): oacc[db] += Vt-frag * Pᵀ
#pragma unroll
        for (int db = 0; db < 2; ++db) {
            const unsigned char* rowp = bp + (db * 32 + r31) * 256;
            f32x16 a = oacc[db];
#pragma unroll
            for (int s = 0; s < 4; ++s) {
                int slot = (8 + 2 * s + hi) ^ rx;
                bf16x8 vf = *reinterpret_cast<const bf16x8*>(rowp + slot * 16);
                a = __builtin_amdgcn_mfma_f32_32x32x16_bf16(vf, pa[s], a, 0, 0, 0);
            }
            oacc[db] = a;
        }

        __syncthreads();
        buf ^= 1;
    }

    // ---- epilogue: write unnormalized O partial (fp32) + (m,l)
    const int q = q0 + r31;
    float* pop = po + (size_t)split * S * E_DIM + (size_t)q * E_DIM + h * HD;
#pragma unroll
    for (int db = 0; db < 2; ++db)
#pragma unroll
        for (int m = 0; m < 4; ++m) {
            float4 v4 = {oacc[db][4 * m + 0], oacc[db][4 * m + 1],
                         oacc[db][4 * m + 2], oacc[db][4 * m + 3]};
            *reinterpret_cast<float4*>(pop + db * 32 + m * 8 + hi * 4) = v4;
        }
    if (hi == 0) {
        float2 v2 = {rm, rl};
        *reinterpret_cast<float2*>(ml + ((size_t)(split * S + q) * NH + h) * 2) = v2;
    }
}

// ---------------- combine K-split partials -> bf16 attnb ----------------
__global__ __launch_bounds__(256)
void combine_kernel(const float* __restrict__ po, const float* __restrict__ ml,
                    __hip_bfloat16* __restrict__ attnb, int S) {
    int idx = blockIdx.x * blockDim.x + threadIdx.x;      // over S*1024
    int qh = idx >> 6;                                    // q*16 + h
    float2 a = *reinterpret_cast<const float2*>(ml + (size_t)qh * 2);
    float2 b = *reinterpret_cast<const float2*>(ml + ((size_t)S * NH + qh) * 2);
    float m = fmaxf(a.x, b.x);
    float w0 = fexp2(a.x - m), w1 = fexp2(b.x - m);
    float l = a.y * w0 + b.y * w1;
    float o = po[idx] * w0 + po[(size_t)S * E_DIM + idx] * w1;
    attnb[idx] = __float2bfloat16(o / l);
}

// ---------------- host launch ----------------
extern "C" void kernel_launch(void* const* d_in, const int* in_sizes, int n_in,
                              void* d_out, int out_size, void* d_ws, size_t ws_size,
                              hipStream_t stream) {
    (void)n_in; (void)out_size; (void)ws_size;
    const float* x  = (const float*)d_in[0];
    const int* mask = (const int*)d_in[1];
    const float* Wq = (const float*)d_in[2];
    const float* bq = (const float*)d_in[3];
    const float* Wk = (const float*)d_in[4];
    const float* bk = (const float*)d_in[5];
    const float* Wv = (const float*)d_in[6];
    const float* bv = (const float*)d_in[7];
    const float* Wo = (const float*)d_in[8];
    const float* bo = (const float*)d_in[9];
    float* out = (float*)d_out;

    const int E = E_DIM;
    const int S = in_sizes[0] / E;

    char* ws = (char*)d_ws;
    size_t off = 0;
    auto alloc = [&](size_t b) { char* p = ws + off; off += (b + 255) & ~(size_t)255; return p; };
    __hip_bfloat16* xb     = (__hip_bfloat16*)alloc((size_t)S * E * 2);
    __hip_bfloat16* wqkvT  = (__hip_bfloat16*)alloc((size_t)QKV_LD * E * 2);  // [Wq^T;Wk^T;Wv^T]
    __hip_bfloat16* woT    = (__hip_bfloat16*)alloc((size_t)E * E * 2);
    __hip_bfloat16* qkvb   = (__hip_bfloat16*)alloc((size_t)S * QKV_LD * 2);
    __hip_bfloat16* vtb    = (__hip_bfloat16*)alloc((size_t)HD * S * 2);
    __hip_bfloat16* attnb  = (__hip_bfloat16*)alloc((size_t)S * E * 2);
    float* bqkv  = (float*)alloc(QKV_LD * 4);
    float* po    = (float*)alloc((size_t)KSPLIT * S * E * 4);
    float* ml    = (float*)alloc((size_t)KSPLIT * S * NH * 2 * 4);
    unsigned long long* mbits = (unsigned long long*)alloc((size_t)S * (S / 64) * 8);

    cast_f32_bf16_kernel<<<dim3((S * E / 4 + 255) / 256), dim3(256), 0, stream>>>(x, xb, S * E);
    transpose_cast_kernel<float><<<dim3(E / 32, E / 32), dim3(256), 0, stream>>>(Wq, E, wqkvT, E, E, E);
    transpose_cast_kernel<float><<<dim3(E / 32, HD / 32), dim3(256), 0, stream>>>(
        Wk, HD, wqkvT + (size_t)E * E, E, E, HD);
    transpose_cast_kernel<float><<<dim3(E / 32, HD / 32), dim3(256), 0, stream>>>(
        Wv, HD, wqkvT + (size_t)(E + HD) * E, E, E, HD);
    transpose_cast_kernel<float><<<dim3(E / 32, E / 32), dim3(256), 0, stream>>>(Wo, E, woT, E, E, E);
    concat_bias3_kernel<<<dim3((QKV_LD + 255) / 256), dim3(256), 0, stream>>>(bq, bk, bv, bqkv);
    maskbits_kernel<<<dim3(1024), dim3(256), 0, stream>>>(mask, mbits, S * (S / 64));

    // fused qkv = x @ [Wq|Wk|Wv] + [bq|bk|bv]; q-part scaled by 1/8*log2e -> bf16 [S][1152]
    gemm_bt_kernel<__hip_bfloat16><<<dim3((S / 128) * (QKV_LD / 128)), dim3(256), 0, stream>>>(
        xb, wqkvT, bqkv, qkvb, S, QKV_LD, E, 0.125f * LOG2E, E, 1.0f);
    // v^T [64][S] from qkv columns 1088..1151
    transpose_cast_kernel<__hip_bfloat16><<<dim3(S / 32, HD / 32), dim3(256), 0, stream>>>(
        qkvb + E + HD, QKV_LD, vtb, S, S, HD);
    // attention partials (K-split flash-decoding)
    mqa4_kernel<<<dim3(S / 32, NH / 4, KSPLIT), dim3(256), 0, stream>>>(
        qkvb, vtb, mbits, po, ml, S);
    // combine partials -> bf16 attnb
    combine_kernel<<<dim3(S * E / 256), dim3(256), 0, stream>>>(po, ml, attnb, S);
    // out = attn @ Wo + bo  (fp32)
    gemm_bt_kernel<float><<<dim3((S / 128) * (E / 128)), dim3(256), 0, stream>>>(
        attnb, woT, bo, out, S, E, E, 1.0f, E, 1.0f);
}

// Round 5
// 181.066 us; speedup vs baseline: 1.3909x; 1.3909x over previous
//
#include <hip/hip_runtime.h>
#include <hip/hip_bf16.h>
#include <stdint.h>

typedef __bf16 bf16x8 __attribute__((ext_vector_type(8)));
typedef float f32x4 __attribute__((ext_vector_type(4)));
typedef float f32x16 __attribute__((ext_vector_type(16)));
typedef unsigned int uint2v __attribute__((ext_vector_type(2)));

#define E_DIM 1024
#define HD 64
#define NH 16
#define QKV_LD 1152
#define LOG2E 1.44269504088896f

__device__ __forceinline__ float toF(float x) { return x; }
__device__ __forceinline__ float toF(__hip_bfloat16 x) { return __bfloat162float(x); }
__device__ __forceinline__ void storeOut(float* p, float v) { *p = v; }
__device__ __forceinline__ void storeOut(__hip_bfloat16* p, float v) { *p = __float2bfloat16(v); }

__device__ __forceinline__ unsigned cvtpk_bf16(float lo, float hi_) {
    unsigned r;
    asm("v_cvt_pk_bf16_f32 %0, %1, %2" : "=v"(r) : "v"(lo), "v"(hi_));
    return r;
}
__device__ __forceinline__ void perm32swap(unsigned& a, unsigned& b) {
    uint2v r = __builtin_amdgcn_permlane32_swap(a, b, false, false);
    a = r.x; b = r.y;
}
__device__ __forceinline__ float fexp2(float x) {
    float r;
    asm("v_exp_f32 %0, %1" : "=v"(r) : "v"(x));
    return r;
}

typedef __attribute__((address_space(1))) void gvoid;
typedef __attribute__((address_space(3))) void lvoid;
__device__ __forceinline__ void gload_lds16(const void* g, void* l) {
    __builtin_amdgcn_global_load_lds((gvoid*)g, (lvoid*)l, 16, 0, 0);
}

// ---------------- cast fp32 -> bf16 (vectorized) ----------------
__global__ void cast_f32_bf16_kernel(const float* __restrict__ in, __hip_bfloat16* __restrict__ o, int n) {
    int i = (blockIdx.x * blockDim.x + threadIdx.x) * 4;
    if (i + 3 < n) {
        float4 v = *reinterpret_cast<const float4*>(in + i);
        __hip_bfloat16 t[4] = {__float2bfloat16(v.x), __float2bfloat16(v.y),
                               __float2bfloat16(v.z), __float2bfloat16(v.w)};
        *reinterpret_cast<uint2*>(o + i) = *reinterpret_cast<uint2*>(t);
    }
}

// ---------------- tiled cast-transpose: out[c][r] = in[r][c] ----------------
template<typename InT>
__global__ void transpose_cast_kernel(const InT* __restrict__ in, int ldi,
                                      __hip_bfloat16* __restrict__ out, int ldo,
                                      int R, int C) {
    __shared__ float tile[32][33];
    const int bx = blockIdx.x * 32;  // r
    const int by = blockIdx.y * 32;  // c
    const int tx = threadIdx.x & 31, ty = threadIdx.x >> 5;  // 32 x 8
#pragma unroll
    for (int j = 0; j < 4; ++j) {
        int r = bx + ty + j * 8, c = by + tx;
        tile[ty + j * 8][tx] = toF(in[(size_t)r * ldi + c]);
    }
    __syncthreads();
#pragma unroll
    for (int j = 0; j < 4; ++j) {
        int c = by + ty + j * 8, r = bx + tx;
        out[(size_t)c * ldo + r] = __float2bfloat16(tile[tx][ty + j * 8]);
    }
}

// ---------------- bqkv = [bq | bk | bv] ----------------
__global__ void concat_bias3_kernel(const float* __restrict__ bq, const float* __restrict__ bk,
                                    const float* __restrict__ bv, float* __restrict__ bqkv) {
    int i = blockIdx.x * blockDim.x + threadIdx.x;
    if (i < E_DIM) bqkv[i] = bq[i];
    else if (i < E_DIM + HD) bqkv[i] = bk[i - E_DIM];
    else if (i < E_DIM + 2 * HD) bqkv[i] = bv[i - E_DIM - HD];
}

// ---------------- mask -> 64-bit words via ballot ----------------
__global__ void maskbits_kernel(const int* __restrict__ mask, unsigned long long* __restrict__ mb,
                                int nwords) {
    int gtid = blockIdx.x * blockDim.x + threadIdx.x;
    int wid = gtid >> 6, lane = gtid & 63;
    int nw = (gridDim.x * blockDim.x) >> 6;
    for (int w = wid; w < nwords; w += nw) {
        int v = mask[(size_t)w * 64 + lane];
        unsigned long long b = __ballot(v != 0);
        if (lane == 0) mb[w] = b;
    }
}

// ---------------- bf16 GEMM v2: BK=64, global_load_lds staging ----------------
// C[M][N] = A[M][K] * Bt[N][K]^T ; epilogue (acc + bias[col]) * (col < nQ ? sQ : sKV)
// LDS rows 128B (8 chunks of 16B); chunk c of row r stored at slot c ^ (r&7)
// (achieved by pre-swizzling the per-lane GLOBAL source; LDS dest stays linear).
template<typename OutT>
__global__ __launch_bounds__(256)
void gemm_bt2_kernel(const __hip_bfloat16* __restrict__ A,
                     const __hip_bfloat16* __restrict__ Bt,
                     const float* __restrict__ bias,
                     OutT* __restrict__ C,
                     int M, int N, int K, float sQ, int nQ, float sKV) {
    constexpr int BM = 128, BN = 128, BK = 64;
    __shared__ __align__(16) unsigned char lA[2][BM * BK * 2];  // 16KB each
    __shared__ __align__(16) unsigned char lB[2][BN * BK * 2];
    const int ntn = N / BN;
    const int tm = blockIdx.x / ntn, tn = blockIdx.x % ntn;
    const int tid = threadIdx.x, lane = tid & 63, wave = tid >> 6;
    const int l15 = lane & 15, l4 = lane >> 4;
    const int wm = (wave >> 1) * 64, wn = (wave & 1) * 64;
    const int r0 = tm * BM, c0 = tn * BN;
    const int NK = K / BK;

    // staging: wave owns rows [wave*32, wave*32+32) of A and B; 4 x 1KB each
    size_t aoff[4], boff[4];      // byte offset of lane's 16B chunk, at k0=0
    unsigned ldso[4];
#pragma unroll
    for (int i = 0; i < 4; ++i) {
        int row = wave * 32 + i * 8 + (lane >> 3);
        int c = (lane & 7) ^ (row & 7);
        aoff[i] = (size_t)(r0 + row) * K * 2 + c * 16;
        boff[i] = (size_t)(c0 + row) * K * 2 + c * 16;
        ldso[i] = wave * 4096 + i * 1024;
    }
    const char* Ab = (const char*)A;
    const char* Bb = (const char*)Bt;

    // prologue: stage k-step 0
#pragma unroll
    for (int i = 0; i < 4; ++i) {
        gload_lds16(Ab + aoff[i], &lA[0][ldso[i]]);
        gload_lds16(Bb + boff[i], &lB[0][ldso[i]]);
    }
    __syncthreads();

    f32x4 z4 = {0.f, 0.f, 0.f, 0.f};
    f32x4 acc[4][4];
#pragma unroll
    for (int mi = 0; mi < 4; ++mi)
#pragma unroll
        for (int ni = 0; ni < 4; ++ni) acc[mi][ni] = z4;

    int buf = 0;
    for (int ks = 0; ks < NK; ++ks) {
        if (ks + 1 < NK) {
            size_t kb = (size_t)(ks + 1) * BK * 2;
#pragma unroll
            for (int i = 0; i < 4; ++i) {
                gload_lds16(Ab + aoff[i] + kb, &lA[buf ^ 1][ldso[i]]);
                gload_lds16(Bb + boff[i] + kb, &lB[buf ^ 1][ldso[i]]);
            }
        }
        bf16x8 af[4][2], bf[4][2];
#pragma unroll
        for (int mi = 0; mi < 4; ++mi) {
            int row = wm + mi * 16 + l15;
#pragma unroll
            for (int kh = 0; kh < 2; ++kh) {
                int slot = (kh * 4 + l4) ^ (row & 7);
                af[mi][kh] = *reinterpret_cast<const bf16x8*>(&lA[buf][row * 128 + slot * 16]);
            }
        }
#pragma unroll
        for (int ni = 0; ni < 4; ++ni) {
            int row = wn + ni * 16 + l15;
#pragma unroll
            for (int kh = 0; kh < 2; ++kh) {
                int slot = (kh * 4 + l4) ^ (row & 7);
                bf[ni][kh] = *reinterpret_cast<const bf16x8*>(&lB[buf][row * 128 + slot * 16]);
            }
        }
        __builtin_amdgcn_s_setprio(1);
#pragma unroll
        for (int mi = 0; mi < 4; ++mi)
#pragma unroll
            for (int ni = 0; ni < 4; ++ni) {
                acc[mi][ni] = __builtin_amdgcn_mfma_f32_16x16x32_bf16(af[mi][0], bf[ni][0], acc[mi][ni], 0, 0, 0);
                acc[mi][ni] = __builtin_amdgcn_mfma_f32_16x16x32_bf16(af[mi][1], bf[ni][1], acc[mi][ni], 0, 0, 0);
            }
        __builtin_amdgcn_s_setprio(0);
        __syncthreads();
        buf ^= 1;
    }

#pragma unroll
    for (int ni = 0; ni < 4; ++ni) {
        int col = c0 + wn + ni * 16 + l15;
        float b = bias[col];
        float s = (col < nQ) ? sQ : sKV;
#pragma unroll
        for (int mi = 0; mi < 4; ++mi) {
            int row = r0 + wm + mi * 16 + l4 * 4;
#pragma unroll
            for (int r = 0; r < 4; ++r) {
                float v = (acc[mi][ni][r] + b) * s;
                storeOut(C + (size_t)(row + r) * N + col, v);
            }
        }
    }
}

// ---------------- MQA flash attention v5: KVBLK=128 ----------------
// grid (S/32, NH/4). 4 waves/block, wave = head, 32 q-rows. Swapped QK^T (q lane-local),
// Oᵀ PV, log2-domain softmax, defer-max, setprio, gload_lds with pre-swizzled source.
// LDS tile: 128 rows x 256B. Row r: chunks 0..7 = K[k0+r][0:64];
// chunks 8..15 = Vt[d = r&63][k0 + (r>>6)*64 .. +64]. Chunk c at slot c ^ (r&15).
__global__ __launch_bounds__(256, 2)
void mqa5_kernel(const __hip_bfloat16* __restrict__ qkv,   // [S][1152], q prescaled
                 const __hip_bfloat16* __restrict__ vtb,   // [64][S]
                 const unsigned long long* __restrict__ mbits,
                 __hip_bfloat16* __restrict__ attnb,
                 int S) {
    __shared__ __align__(16) unsigned char sKV[2][32768];
    const int tid = threadIdx.x, lane = tid & 63, w = tid >> 6;
    const int r31 = lane & 31, hi = lane >> 5, rx = r31 & 15;
    const int q0 = blockIdx.x * 32;
    const int h = blockIdx.y * 4 + w;
    const int NT = S / 128, NW64 = S / 64;
    const __hip_bfloat16* kvb = qkv + E_DIM;

    // Q fragments (prescaled by 0.125*log2e in the fused GEMM)
    bf16x8 qf[4];
    {
        const __hip_bfloat16* qp = qkv + (size_t)(q0 + r31) * QKV_LD + h * HD + hi * 8;
#pragma unroll
        for (int s = 0; s < 4; ++s) qf[s] = *reinterpret_cast<const bf16x8*>(qp + 16 * s);
    }

    // staging: wave w owns tile rows [w*32, w*32+32) -> 8 x 1KB global_load_lds_dwordx4
    const char* gbase[8];
    int gstep[8];
    unsigned ldsoff[8];
#pragma unroll
    for (int i = 0; i < 8; ++i) {
        int r = w * 32 + i * 4 + (lane >> 4);
        int sl = lane & 15;            // LDS 16B slot within row
        int c = sl ^ (r & 15);         // global chunk that lands in this slot
        if (c < 8) {
            gbase[i] = (const char*)(kvb + (size_t)r * QKV_LD + c * 8);
            gstep[i] = 128 * QKV_LD * 2;
        } else {
            gbase[i] = (const char*)(vtb + (size_t)(r & 63) * S + (r >> 6) * 64 + (c - 8) * 8);
            gstep[i] = 128 * 2;
        }
        ldsoff[i] = w * 8192 + i * 1024;
    }

    // prologue: stage tile 0
#pragma unroll
    for (int i = 0; i < 8; ++i) { gload_lds16(gbase[i], &sKV[0][ldsoff[i]]); gbase[i] += gstep[i]; }
    __syncthreads();

    float rm = -3e38f, rl = 0.f;
    f32x16 oacc[2];
#pragma unroll
    for (int i = 0; i < 16; ++i) { oacc[0][i] = 0.f; oacc[1][i] = 0.f; }

    int buf = 0;
    for (int t = 0; t < NT; ++t) {
        // stage tile t+1 into other buffer (drained by end-of-iter barrier)
        if (t + 1 < NT) {
#pragma unroll
            for (int i = 0; i < 8; ++i) { gload_lds16(gbase[i], &sKV[buf ^ 1][ldsoff[i]]); gbase[i] += gstep[i]; }
        }
        ulonglong2 wb = *reinterpret_cast<const ulonglong2*>(
            mbits + (size_t)(q0 + r31) * NW64 + 2 * t);
        const unsigned char* bp = sKV[buf];

        // ---- QK^T: sacc[kb][reg] = S_log2[k = kb*32 + crow(reg,hi)][q = r31]
        f32x16 sacc[4];
        __builtin_amdgcn_s_setprio(1);
#pragma unroll
        for (int kb = 0; kb < 4; ++kb) {
            const unsigned char* rowp = bp + (kb * 32 + r31) * 256;
            f32x16 a;
#pragma unroll
            for (int i = 0; i < 16; ++i) a[i] = 0.f;
#pragma unroll
            for (int s = 0; s < 4; ++s) {
                int slot = (2 * s + hi) ^ rx;
                bf16x8 kf = *reinterpret_cast<const bf16x8*>(rowp + slot * 16);
                a = __builtin_amdgcn_mfma_f32_32x32x16_bf16(kf, qf[s], a, 0, 0, 0);
            }
            sacc[kb] = a;
        }
        __builtin_amdgcn_s_setprio(0);

        // ---- mask (free when all-ones); -10000 * log2e
        if ((wb.x & wb.y) != ~0ull) {
#pragma unroll
            for (int kb = 0; kb < 4; ++kb) {
                unsigned long long wv = (kb < 2) ? wb.x : wb.y;
                int base = (kb & 1) * 32;
#pragma unroll
                for (int r = 0; r < 16; ++r) {
                    int kl = base + (r & 3) + 8 * (r >> 2) + 4 * hi;
                    if (!((wv >> kl) & 1)) sacc[kb][r] = -14427.0f;
                }
            }
        }

        // ---- tile max (ILP tree over 64 values) + one cross-half exchange
        float t0[8];
#pragma unroll
        for (int j = 0; j < 8; ++j) {
            float a01 = fmaxf(fmaxf(sacc[0][j], sacc[0][j + 8]), fmaxf(sacc[1][j], sacc[1][j + 8]));
            float a23 = fmaxf(fmaxf(sacc[2][j], sacc[2][j + 8]), fmaxf(sacc[3][j], sacc[3][j + 8]));
            t0[j] = fmaxf(a01, a23);
        }
        float u0 = fmaxf(t0[0], t0[4]), u1 = fmaxf(t0[1], t0[5]);
        float u2 = fmaxf(t0[2], t0[6]), u3 = fmaxf(t0[3], t0[7]);
        float pmax = fmaxf(fmaxf(u0, u1), fmaxf(u2, u3));
        pmax = fmaxf(pmax, __shfl_xor(pmax, 32));

        // ---- defer-max: rescale only when needed (wave-uniform branch)
        if (!__all(pmax - rm <= 8.0f)) {
            float rmn = fmaxf(rm, pmax);
            float al = fexp2(rm - rmn);
            rl *= al;
#pragma unroll
            for (int r = 0; r < 16; ++r) { oacc[0][r] *= al; oacc[1][r] *= al; }
            rm = rmn;
        }

        // ---- p = exp2(s - rm), 4-way partial sums
        float s0 = 0.f, s1 = 0.f, s2 = 0.f, s3 = 0.f;
#pragma unroll
        for (int kb = 0; kb < 4; ++kb) {
#pragma unroll
            for (int r = 0; r < 16; r += 4) {
                sacc[kb][r + 0] = fexp2(sacc[kb][r + 0] - rm); s0 += sacc[kb][r + 0];
                sacc[kb][r + 1] = fexp2(sacc[kb][r + 1] - rm); s1 += sacc[kb][r + 1];
                sacc[kb][r + 2] = fexp2(sacc[kb][r + 2] - rm); s2 += sacc[kb][r + 2];
                sacc[kb][r + 3] = fexp2(sacc[kb][r + 3] - rm); s3 += sacc[kb][r + 3];
            }
        }
        float sum = (s0 + s1) + (s2 + s3);
        sum += __shfl_xor(sum, 32);
        rl += sum;

        // ---- P -> bf16 A-frags: pa[u] holds P[q=r31][k = u*16 + hi*8 + j], u=0..7
        bf16x8 pa[8];
#pragma unroll
        for (int kb = 0; kb < 4; ++kb) {
#pragma unroll
            for (int half = 0; half < 2; ++half) {
                int b0 = half * 8;
                unsigned A = cvtpk_bf16(sacc[kb][b0 + 0], sacc[kb][b0 + 1]);
                unsigned B = cvtpk_bf16(sacc[kb][b0 + 2], sacc[kb][b0 + 3]);
                unsigned C = cvtpk_bf16(sacc[kb][b0 + 4], sacc[kb][b0 + 5]);
                unsigned D = cvtpk_bf16(sacc[kb][b0 + 6], sacc[kb][b0 + 7]);
                perm32swap(A, C);
                perm32swap(B, D);
                union { unsigned u[4]; bf16x8 v; } pk;
                pk.u[0] = A; pk.u[1] = B; pk.u[2] = C; pk.u[3] = D;
                pa[kb * 2 + half] = pk.v;
            }
        }

        // ---- PV (Oᵀ): oacc[db] += Vt-frag * Pᵀ over both k-halves
        __builtin_amdgcn_s_setprio(1);
#pragma unroll
        for (int db = 0; db < 2; ++db) {
            f32x16 a = oacc[db];
#pragma unroll
            for (int j = 0; j < 2; ++j) {
                const unsigned char* rowp = bp + (j * 64 + db * 32 + r31) * 256;
#pragma unroll
                for (int s = 0; s < 4; ++s) {
                    int slot = (8 + 2 * s + hi) ^ rx;
                    bf16x8 vf = *reinterpret_cast<const bf16x8*>(rowp + slot * 16);
                    a = __builtin_amdgcn_mfma_f32_32x32x16_bf16(vf, pa[j * 4 + s], a, 0, 0, 0);
                }
            }
            oacc[db] = a;
        }
        __builtin_amdgcn_s_setprio(0);

        __syncthreads();
        buf ^= 1;
    }

    // ---- epilogue: O /= l ; d = db*32 + 8m + 4hi + i
    float inv = 1.0f / rl;
    __hip_bfloat16* op = attnb + (size_t)(q0 + r31) * E_DIM + h * HD;
#pragma unroll
    for (int db = 0; db < 2; ++db)
#pragma unroll
        for (int m = 0; m < 4; ++m) {
            uint2 pk;
            pk.x = cvtpk_bf16(oacc[db][4 * m + 0] * inv, oacc[db][4 * m + 1] * inv);
            pk.y = cvtpk_bf16(oacc[db][4 * m + 2] * inv, oacc[db][4 * m + 3] * inv);
            *reinterpret_cast<uint2*>(op + db * 32 + m * 8 + hi * 4) = pk;
        }
}

// ---------------- host launch ----------------
extern "C" void kernel_launch(void* const* d_in, const int* in_sizes, int n_in,
                              void* d_out, int out_size, void* d_ws, size_t ws_size,
                              hipStream_t stream) {
    (void)n_in; (void)out_size; (void)ws_size;
    const float* x  = (const float*)d_in[0];
    const int* mask = (const int*)d_in[1];
    const float* Wq = (const float*)d_in[2];
    const float* bq = (const float*)d_in[3];
    const float* Wk = (const float*)d_in[4];
    const float* bk = (const float*)d_in[5];
    const float* Wv = (const float*)d_in[6];
    const float* bv = (const float*)d_in[7];
    const float* Wo = (const float*)d_in[8];
    const float* bo = (const float*)d_in[9];
    float* out = (float*)d_out;

    const int E = E_DIM;
    const int S = in_sizes[0] / E;

    char* ws = (char*)d_ws;
    size_t off = 0;
    auto alloc = [&](size_t b) { char* p = ws + off; off += (b + 255) & ~(size_t)255; return p; };
    __hip_bfloat16* xb     = (__hip_bfloat16*)alloc((size_t)S * E * 2);
    __hip_bfloat16* wqkvT  = (__hip_bfloat16*)alloc((size_t)QKV_LD * E * 2);  // [Wq^T;Wk^T;Wv^T]
    __hip_bfloat16* woT    = (__hip_bfloat16*)alloc((size_t)E * E * 2);
    __hip_bfloat16* qkvb   = (__hip_bfloat16*)alloc((size_t)S * QKV_LD * 2);
    __hip_bfloat16* vtb    = (__hip_bfloat16*)alloc((size_t)HD * S * 2);
    __hip_bfloat16* attnb  = (__hip_bfloat16*)alloc((size_t)S * E * 2);
    float* bqkv  = (float*)alloc(QKV_LD * 4);
    unsigned long long* mbits = (unsigned long long*)alloc((size_t)S * (S / 64) * 8);

    cast_f32_bf16_kernel<<<dim3((S * E / 4 + 255) / 256), dim3(256), 0, stream>>>(x, xb, S * E);
    transpose_cast_kernel<float><<<dim3(E / 32, E / 32), dim3(256), 0, stream>>>(Wq, E, wqkvT, E, E, E);
    transpose_cast_kernel<float><<<dim3(E / 32, HD / 32), dim3(256), 0, stream>>>(
        Wk, HD, wqkvT + (size_t)E * E, E, E, HD);
    transpose_cast_kernel<float><<<dim3(E / 32, HD / 32), dim3(256), 0, stream>>>(
        Wv, HD, wqkvT + (size_t)(E + HD) * E, E, E, HD);
    transpose_cast_kernel<float><<<dim3(E / 32, E / 32), dim3(256), 0, stream>>>(Wo, E, woT, E, E, E);
    concat_bias3_kernel<<<dim3((QKV_LD + 255) / 256), dim3(256), 0, stream>>>(bq, bk, bv, bqkv);
    maskbits_kernel<<<dim3(1024), dim3(256), 0, stream>>>(mask, mbits, S * (S / 64));

    // fused qkv = x @ [Wq|Wk|Wv] + [bq|bk|bv]; q-part scaled by 1/8*log2e -> bf16 [S][1152]
    gemm_bt2_kernel<__hip_bfloat16><<<dim3((S / 128) * (QKV_LD / 128)), dim3(256), 0, stream>>>(
        xb, wqkvT, bqkv, qkvb, S, QKV_LD, E, 0.125f * LOG2E, E, 1.0f);
    // v^T [64][S] from qkv columns 1088..1151
    transpose_cast_kernel<__hip_bfloat16><<<dim3(S / 32, HD / 32), dim3(256), 0, stream>>>(
        qkvb + E + HD, QKV_LD, vtb, S, S, HD);
    // attention (merged-head MQA, swapped-QK^T flash, KVBLK=128)
    mqa5_kernel<<<dim3(S / 32, NH / 4), dim3(256), 0, stream>>>(qkvb, vtb, mbits, attnb, S);
    // out = attn @ Wo + bo  (fp32)
    gemm_bt2_kernel<float><<<dim3((S / 128) * (E / 128)), dim3(256), 0, stream>>>(
        attnb, woT, bo, out, S, E, E, 1.0f, E, 1.0f);
}